// Round 6
// baseline (680.859 us; speedup 1.0000x reference)
//
#include <hip/hip_runtime.h>
#include <math.h>

#define N_NODES 50000
#define N_EDGES 800000
#define N_ADJS  6
#define NHID    256
#define BSHIFT  7         // 128-row buckets
#define NB      391       // ceil(50000/128)
#define SLOTCAP 2560      // fixed slot capacity per bucket (mean fill ~2046, max ~2250)
#define BCAP    2816      // LDS sort capacity in build_csr
#define EPB     2048      // edges per block in bucket_scatter
#define PULL_BLOCKS 1536  // 6 blocks/CU * 256 CU: fully resident persistent grid
#define PULL_WAVES  (PULL_BLOCKS * 4)
#define RMAX    9         // max rows per wave: ceil(50000/6144)
#define LN_EPS  1e-5f

typedef _Float16 f16x8 __attribute__((ext_vector_type(8)));
typedef float f32x4  __attribute__((ext_vector_type(4)));
typedef _Float16 h4  __attribute__((ext_vector_type(4)));   // 8-byte fp16 quad

// -------------------- W -> fp16 --------------------
__global__ __launch_bounds__(256) void convert_w(const float* __restrict__ W,
                                                 _Float16* __restrict__ Wh)
{
    const int i = blockIdx.x * 256 + threadIdx.x;   // 65536 total
    Wh[i] = (_Float16)W[i];
}

// -------------------- h = x @ W^T + b via MFMA (fp16 in, fp32 acc) --------------------
__global__ __launch_bounds__(256) void gemm_mfma(const float* __restrict__ x,
                                                 const _Float16* __restrict__ Wh,
                                                 const float* __restrict__ bias,
                                                 _Float16* __restrict__ h)
{
    const int tid = threadIdx.x;
    const int w = tid >> 6, l = tid & 63;
    const int m = l & 15, q = l >> 4;
    const int row0 = blockIdx.x * 64 + w * 16;
    const int arow = row0 + m;
    const int arow_c = (arow < N_NODES) ? arow : 0;

    f32x4 acc[16];
    #pragma unroll
    for (int nt = 0; nt < 16; ++nt) acc[nt] = (f32x4){0.f, 0.f, 0.f, 0.f};

    for (int kt = 0; kt < NHID; kt += 32) {
        const float* xp = x + (size_t)arow_c * NHID + kt + q * 8;
        const float4 xa = *(const float4*)xp;
        const float4 xb = *(const float4*)(xp + 4);
        f16x8 ah;
        ah[0] = (_Float16)xa.x; ah[1] = (_Float16)xa.y;
        ah[2] = (_Float16)xa.z; ah[3] = (_Float16)xa.w;
        ah[4] = (_Float16)xb.x; ah[5] = (_Float16)xb.y;
        ah[6] = (_Float16)xb.z; ah[7] = (_Float16)xb.w;
        const int ko = kt + q * 8;
        #pragma unroll
        for (int nt = 0; nt < 16; ++nt) {
            const size_t off = (size_t)(nt * 16 + m) * NHID + ko;
            const f16x8 bh = *(const f16x8*)(Wh + off);
            acc[nt] = __builtin_amdgcn_mfma_f32_16x16x32_f16(ah, bh, acc[nt], 0, 0, 0);
        }
    }

    // C/D: col = lane&15, row = (lane>>4)*4 + reg
    #pragma unroll
    for (int nt = 0; nt < 16; ++nt) {
        const int col = nt * 16 + m;
        const float bv = bias[col];
        #pragma unroll
        for (int r = 0; r < 4; ++r) {
            const int grow = row0 + q * 4 + r;
            if (grow < N_NODES) h[(size_t)grow * NHID + col] = (_Float16)(acc[nt][r] + bv);
        }
    }
}

// -------------------- CSR build, pass A: LDS-presorted slotted scatter --------------------
// Block sorts its 2048 edges by bucket in LDS (counting sort), reserves global
// ranges, then writes each bucket's run contiguously -> coalesced ~42B runs
// instead of fully-random 8B scatter. gcnt ends as final bucket counts.
__global__ __launch_bounds__(256) void bucket_scatter(const int* __restrict__ rows_all,
                                                      const int* __restrict__ cols_all,
                                                      const float* __restrict__ vals_all,
                                                      int* __restrict__ gcnt,
                                                      int2* __restrict__ slots)
{
    const int a = blockIdx.y;
    __shared__ int2 buf[EPB];      // 16 KB
    __shared__ int2 buf2[EPB];     // 16 KB
    __shared__ int lcnt[NB], lscan[NB], lcur[NB], lbase[NB];  // 6.2 KB
    for (int i = threadIdx.x; i < NB; i += 256) lcnt[i] = 0;
    __syncthreads();
    const int e0 = blockIdx.x * EPB;
    const int n = min(EPB, N_EDGES - e0);
    for (int i = threadIdx.x; i < n; i += 256) {
        const size_t idx = (size_t)a * N_EDGES + e0 + i;
        const int r = rows_all[idx];
        int2 pq;
        pq.x = (r << 16) | cols_all[idx];
        pq.y = __float_as_int(vals_all[idx]);
        buf[i] = pq;
        atomicAdd(&lcnt[r >> BSHIFT], 1);
    }
    __syncthreads();
    if (threadIdx.x < 64) {
        const int lane = threadIdx.x;
        int carry = 0;
        #pragma unroll
        for (int c = 0; c < 7; ++c) {
            const int i = c * 64 + lane;
            const int v = (i < NB) ? lcnt[i] : 0;
            int xs = v;
            #pragma unroll
            for (int d = 1; d < 64; d <<= 1) { const int t = __shfl_up(xs, d, 64); if (lane >= d) xs += t; }
            const int excl = carry + xs - v;
            if (i < NB) {
                lscan[i] = excl; lcur[i] = excl;
                lbase[i] = v ? atomicAdd(&gcnt[a * NB + i], v) : 0;
            }
            carry += __shfl(xs, 63, 64);
        }
    }
    __syncthreads();
    for (int i = threadIdx.x; i < n; i += 256) {
        const int2 p = buf[i];
        const unsigned r = ((unsigned)p.x) >> 16;
        const int pos = atomicAdd(&lcur[r >> BSHIFT], 1);
        buf2[pos] = p;
    }
    __syncthreads();
    for (int i = threadIdx.x; i < n; i += 256) {
        const int2 p = buf2[i];
        const unsigned r = ((unsigned)p.x) >> 16;
        const int b = r >> BSHIFT;
        slots[((size_t)a * NB + b) * SLOTCAP + lbase[b] + (i - lscan[b])] = p;
    }
}

// -------------------- CSR build: scan final counts -> compacted bstart --------------------
__global__ __launch_bounds__(384) void scan_buckets(const int* __restrict__ gcnt,
                                                    int* __restrict__ bstart,
                                                    int* __restrict__ row_start)
{
    const int lane = threadIdx.x & 63, a = threadIdx.x >> 6;
    if (a >= N_ADJS) return;
    int carry = 0;
    #pragma unroll
    for (int c = 0; c < 7; ++c) {
        const int i = c * 64 + lane;
        const int v = (i < NB) ? gcnt[a * NB + i] : 0;
        int xs = v;
        #pragma unroll
        for (int d = 1; d < 64; d <<= 1) { const int t = __shfl_up(xs, d, 64); if (lane >= d) xs += t; }
        const int excl = carry + xs - v;
        if (i < NB) bstart[a * (NB + 1) + i] = excl;
        carry += __shfl(xs, 63, 64);
    }
    if (lane == 0) {
        bstart[a * (NB + 1) + NB] = N_EDGES;
        row_start[(size_t)a * (N_NODES + 1) + N_NODES] = N_EDGES;
    }
}

// -------------------- CSR build, pass B: LDS-staged per-bucket row sort --------------------
__global__ __launch_bounds__(256) void build_csr(const int2* __restrict__ slots,
                                                 const int* __restrict__ bstart,
                                                 int* __restrict__ row_start,
                                                 int2* __restrict__ sorted_cv)
{
    const int a = blockIdx.y, b = blockIdx.x;
    const int s = bstart[a * (NB + 1) + b];
    const int n = bstart[a * (NB + 1) + b + 1] - s;
    __shared__ int cnt[128], cur[128];
    __shared__ int2 buf[BCAP];    // 22 KB
    __shared__ int2 buf2[BCAP];   // 22 KB
    if (threadIdx.x < 128) cnt[threadIdx.x] = 0;
    __syncthreads();
    const int2* bk = slots + ((size_t)a * NB + b) * SLOTCAP;
    const bool fits = (n <= BCAP);
    for (int i = threadIdx.x; i < n; i += 256) {
        const int2 p = bk[i];
        if (fits) buf[i] = p;
        atomicAdd(&cnt[(p.x >> 16) & 127], 1);
    }
    __syncthreads();
    const int lane = threadIdx.x & 63, wid = threadIdx.x >> 6;
    if (wid == 0) {
        const int i0 = lane * 2;
        const int c0 = cnt[i0], c1 = cnt[i0 + 1];
        const int sum = c0 + c1;
        int xs = sum;
        #pragma unroll
        for (int d = 1; d < 64; d <<= 1) { const int t = __shfl_up(xs, d, 64); if (lane >= d) xs += t; }
        const int base = xs - sum;        // exclusive, local to bucket
        const int o0 = base, o1 = base + c0;
        cur[i0] = o0; cur[i0 + 1] = o1;
        int* rs = row_start + (size_t)a * (N_NODES + 1);
        const int gr = (b << BSHIFT) + i0;
        if (gr + 0 < N_NODES) rs[gr + 0] = s + o0;
        if (gr + 1 < N_NODES) rs[gr + 1] = s + o1;
    }
    __syncthreads();
    int2* sc = sorted_cv + (size_t)a * N_EDGES;
    if (fits) {
        for (int i = threadIdx.x; i < n; i += 256) {
            const int2 p = buf[i];
            const int pos = atomicAdd(&cur[(p.x >> 16) & 127], 1);
            int2 cv; cv.x = p.x & 0xFFFF; cv.y = p.y;
            buf2[pos] = cv;
        }
        __syncthreads();
        for (int i = threadIdx.x; i < n; i += 256)
            sc[s + i] = buf2[i];                    // coalesced streaming write
    } else {
        for (int i = threadIdx.x; i < n; i += 256) {
            const int2 p = bk[i];
            const int pos = atomicAdd(&cur[(p.x >> 16) & 127], 1);
            int2 cv; cv.x = p.x & 0xFFFF; cv.y = p.y;
            sc[s + pos] = cv;
        }
    }
}

// -------------------- pull-mode SpMM over fp16 states, fp32 accumulate --------------------
static __device__ __forceinline__ void gacc(const _Float16* __restrict__ src,
                                            int col, float v, int lane, f32x4& acc)
{
    const h4 g = *(const h4*)(src + (size_t)col * NHID + lane * 4);
    acc[0] += v * (float)g[0];
    acc[1] += v * (float)g[1];
    acc[2] += v * (float)g[2];
    acc[3] += v * (float)g[3];
}

static __device__ __forceinline__ void pull_part(const int* __restrict__ row_start,
                                                 const int2* __restrict__ sorted_cv,
                                                 int a, const _Float16* __restrict__ src,
                                                 int row, int lane, f32x4& acc)
{
    const int2* cv = sorted_cv + (size_t)a * N_EDGES;
    const int* rs  = row_start + (size_t)a * (N_NODES + 1);
    const int s = rs[row], epnd = rs[row + 1];
    int e = s;
    for (; e + 3 < epnd; e += 4) {
        const int2 p0 = cv[e];
        const int2 p1 = cv[e + 1];
        const int2 p2 = cv[e + 2];
        const int2 p3 = cv[e + 3];
        gacc(src, p0.x, __int_as_float(p0.y), lane, acc);
        gacc(src, p1.x, __int_as_float(p1.y), lane, acc);
        gacc(src, p2.x, __int_as_float(p2.y), lane, acc);
        gacc(src, p3.x, __int_as_float(p3.y), lane, acc);
    }
    for (; e < epnd; ++e) {
        const int2 p0 = cv[e];
        gacc(src, p0.x, __int_as_float(p0.y), lane, acc);
    }
}

// Persistent phased pull: grid fully resident (1536 blocks); each wave owns a
// contiguous ~8-9 row range with acc in registers; parts loop is OUTERMOST so
// the whole GPU gathers from ONE 25.6 MB source at a time (phase footprint
// 76.8 -> 25.6 MB => better L2/L3 absorption). Per-row accumulation order is
// unchanged (a then b then c) => bit-identical output.
template<int PARTS, bool LN>
__global__ __launch_bounds__(256, 6) void pull_phased(
    const int* __restrict__ row_start, const int2* __restrict__ sorted_cv,
    const int* __restrict__ idx_a, int pos_a, const _Float16* __restrict__ src_a,
    const int* __restrict__ idx_b, int pos_b, const _Float16* __restrict__ src_b,
    const int* __restrict__ idx_c, int pos_c, const _Float16* __restrict__ src_c,
    _Float16* __restrict__ outh, float* __restrict__ outf,
    const float* __restrict__ gamma, const float* __restrict__ beta)
{
    const int wave = blockIdx.x * 4 + (threadIdx.x >> 6);
    const int lane = threadIdx.x & 63;
    const int r0 = (int)((long long)wave * N_NODES / PULL_WAVES);
    const int r1 = (int)((long long)(wave + 1) * N_NODES / PULL_WAVES);
    const int nr = r1 - r0;          // 8 or 9

    f32x4 acc[RMAX];
    #pragma unroll
    for (int k = 0; k < RMAX; ++k) acc[k] = (f32x4){0.f, 0.f, 0.f, 0.f};

    {
        const int a = idx_a[pos_a];
        #pragma unroll
        for (int k = 0; k < RMAX; ++k)
            if (k < nr) pull_part(row_start, sorted_cv, a, src_a, r0 + k, lane, acc[k]);
    }
    if constexpr (PARTS >= 2) {
        const int a = idx_b[pos_b];
        #pragma unroll
        for (int k = 0; k < RMAX; ++k)
            if (k < nr) pull_part(row_start, sorted_cv, a, src_b, r0 + k, lane, acc[k]);
    }
    if constexpr (PARTS >= 3) {
        const int a = idx_c[pos_c];
        #pragma unroll
        for (int k = 0; k < RMAX; ++k)
            if (k < nr) pull_part(row_start, sorted_cv, a, src_c, r0 + k, lane, acc[k]);
    }

    if constexpr (LN) {
        const float4 g4 = *(const float4*)(gamma + lane * 4);
        const float4 b4 = *(const float4*)(beta + lane * 4);
        const float g[4]  = {g4.x, g4.y, g4.z, g4.w};
        const float bb[4] = {b4.x, b4.y, b4.z, b4.w};
        #pragma unroll
        for (int k = 0; k < RMAX; ++k) {
            if (k < nr) {
                float sum = acc[k][0] + acc[k][1] + acc[k][2] + acc[k][3];
                float sq  = acc[k][0]*acc[k][0] + acc[k][1]*acc[k][1]
                          + acc[k][2]*acc[k][2] + acc[k][3]*acc[k][3];
                #pragma unroll
                for (int off = 1; off < 64; off <<= 1) {
                    sum += __shfl_xor(sum, off, 64);
                    sq  += __shfl_xor(sq,  off, 64);
                }
                const float mu   = sum * (1.f / NHID);
                const float var  = sq * (1.f / NHID) - mu * mu;
                const float rstd = rsqrtf(var + LN_EPS);
                f32x4 o;
                #pragma unroll
                for (int j = 0; j < 4; ++j) {
                    const float y = (acc[k][j] - mu) * rstd * g[j] + bb[j];
                    o[j] = 0.5f * y * (1.f + erff(y * 0.70710678118654752f));
                }
                __builtin_nontemporal_store(o, (f32x4*)(outf + (size_t)(r0 + k) * NHID + lane * 4));
            }
        }
    } else {
        #pragma unroll
        for (int k = 0; k < RMAX; ++k) {
            if (k < nr) {
                h4 o;
                o[0] = (_Float16)acc[k][0]; o[1] = (_Float16)acc[k][1];
                o[2] = (_Float16)acc[k][2]; o[3] = (_Float16)acc[k][3];
                __builtin_nontemporal_store(o, (h4*)(outh + (size_t)(r0 + k) * NHID + lane * 4));
            }
        }
    }
}

extern "C" void kernel_launch(void* const* d_in, const int* in_sizes, int n_in,
                              void* d_out, int out_size, void* d_ws, size_t ws_size,
                              hipStream_t stream)
{
    (void)in_sizes; (void)n_in; (void)out_size; (void)ws_size;
    const float* x        = (const float*)d_in[0];
    const int* adj_rows   = (const int*)d_in[1];
    const int* adj_cols   = (const int*)d_in[2];
    const float* vals     = (const float*)d_in[3];
    const int* idx_seq    = (const int*)d_in[4];
    const int* idx_res    = (const int*)d_in[5];
    const float* W        = (const float*)d_in[6];
    const float* bias     = (const float*)d_in[7];
    const float* gam      = (const float*)d_in[8];
    const float* bet      = (const float*)d_in[9];

    const size_t S = (size_t)N_NODES * NHID;
    _Float16* s0 = (_Float16*)d_ws;            // 25.6 MB each
    _Float16* s1 = s0 + S;
    _Float16* s2 = s1 + S;
    int2*  sorted_cv      = (int2*)(s2 + S);                                  // 38.4 MB
    int*   row_start      = (int*)(sorted_cv + (size_t)N_ADJS * N_EDGES);     // 1.2 MB
    _Float16* Wh          = (_Float16*)(row_start + (size_t)N_ADJS * (N_NODES + 1)); // 128 KB
    int*   gcnt           = (int*)(Wh + NHID * NHID);
    int*   bstart         = gcnt + N_ADJS * NB;
    // slots alias s1+s2: 6*391*2560*8 = 48.0 MB <= 51.2 MB; dead before pull1 writes s1.
    int2*  slots          = (int2*)s1;

    hipMemsetAsync(gcnt, 0, (size_t)N_ADJS * NB * sizeof(int), stream);

    convert_w<<<dim3(NHID * NHID / 256), dim3(256), 0, stream>>>(W, Wh);
    gemm_mfma<<<dim3((N_NODES + 63) / 64), dim3(256), 0, stream>>>(x, Wh, bias, s0);

    const int eblocks = (N_EDGES + EPB - 1) / EPB;
    bucket_scatter<<<dim3(eblocks, N_ADJS), dim3(256), 0, stream>>>(adj_rows, adj_cols, vals, gcnt, slots);
    scan_buckets<<<dim3(1), dim3(384), 0, stream>>>(gcnt, bstart, row_start);
    build_csr<<<dim3(NB, N_ADJS), dim3(256), 0, stream>>>(slots, bstart, row_start, sorted_cv);

    const dim3 pgrid(PULL_BLOCKS);
    pull_phased<1, false><<<pgrid, dim3(256), 0, stream>>>(row_start, sorted_cv,
        idx_seq, 0, s0,  nullptr, 0, nullptr,  nullptr, 0, nullptr,
        s1, nullptr, nullptr, nullptr);
    pull_phased<2, false><<<pgrid, dim3(256), 0, stream>>>(row_start, sorted_cv,
        idx_seq, 1, s1,  idx_res, 0, s0,  nullptr, 0, nullptr,
        s2, nullptr, nullptr, nullptr);
    pull_phased<3, true><<<pgrid, dim3(256), 0, stream>>>(row_start, sorted_cv,
        idx_seq, 2, s2,  idx_res, 1, s0,  idx_res, 2, s1,
        nullptr, (float*)d_out, gam, bet);
}

// Round 8
// 672.312 us; speedup vs baseline: 1.0127x; 1.0127x over previous
//
#include <hip/hip_runtime.h>
#include <math.h>

#define N_NODES 50000
#define N_EDGES 800000
#define N_ADJS  6
#define NHID    256
#define BSHIFT  7         // 128-row buckets
#define NB      391       // ceil(50000/128)
#define SLOTCAP 2560      // fixed slot capacity per bucket (mean fill ~2046, max ~2250)
#define BCAP    2816      // LDS sort capacity in build_csr
#define EPB     3072      // edges per block in bucket_scatter (54.2 KB LDS < 64 KB limit)
#define GPAD    16        // pad atomic counters to own 64B line
#define LN_EPS  1e-5f

typedef _Float16 f16x8 __attribute__((ext_vector_type(8)));
typedef float f32x4  __attribute__((ext_vector_type(4)));
typedef _Float16 h4  __attribute__((ext_vector_type(4)));   // 8-byte fp16 quad

// -------------------- W -> fp16 (+ zero padded atomic counters) --------------------
__global__ __launch_bounds__(256) void convert_w(const float* __restrict__ W,
                                                 _Float16* __restrict__ Wh,
                                                 int* __restrict__ gcnt,
                                                 int* __restrict__ cursor)
{
    const int i = blockIdx.x * 256 + threadIdx.x;   // 65536 total
    Wh[i] = (_Float16)W[i];
    if (i < N_ADJS * NB) gcnt[i * GPAD] = 0;
    if (i < N_ADJS) cursor[i * GPAD] = 0;
}

// -------------------- h = x @ W^T + b via MFMA (fp16 in, fp32 acc) --------------------
__global__ __launch_bounds__(256) void gemm_mfma(const float* __restrict__ x,
                                                 const _Float16* __restrict__ Wh,
                                                 const float* __restrict__ bias,
                                                 _Float16* __restrict__ h)
{
    const int tid = threadIdx.x;
    const int w = tid >> 6, l = tid & 63;
    const int m = l & 15, q = l >> 4;
    const int row0 = blockIdx.x * 64 + w * 16;
    const int arow = row0 + m;
    const int arow_c = (arow < N_NODES) ? arow : 0;

    f32x4 acc[16];
    #pragma unroll
    for (int nt = 0; nt < 16; ++nt) acc[nt] = (f32x4){0.f, 0.f, 0.f, 0.f};

    for (int kt = 0; kt < NHID; kt += 32) {
        const float* xp = x + (size_t)arow_c * NHID + kt + q * 8;
        const float4 xa = *(const float4*)xp;
        const float4 xb = *(const float4*)(xp + 4);
        f16x8 ah;
        ah[0] = (_Float16)xa.x; ah[1] = (_Float16)xa.y;
        ah[2] = (_Float16)xa.z; ah[3] = (_Float16)xa.w;
        ah[4] = (_Float16)xb.x; ah[5] = (_Float16)xb.y;
        ah[6] = (_Float16)xb.z; ah[7] = (_Float16)xb.w;
        const int ko = kt + q * 8;
        #pragma unroll
        for (int nt = 0; nt < 16; ++nt) {
            const size_t off = (size_t)(nt * 16 + m) * NHID + ko;
            const f16x8 bh = *(const f16x8*)(Wh + off);
            acc[nt] = __builtin_amdgcn_mfma_f32_16x16x32_f16(ah, bh, acc[nt], 0, 0, 0);
        }
    }

    // C/D: col = lane&15, row = (lane>>4)*4 + reg
    #pragma unroll
    for (int nt = 0; nt < 16; ++nt) {
        const int col = nt * 16 + m;
        const float bv = bias[col];
        #pragma unroll
        for (int r = 0; r < 4; ++r) {
            const int grow = row0 + q * 4 + r;
            if (grow < N_NODES) h[(size_t)grow * NHID + col] = (_Float16)(acc[nt][r] + bv);
        }
    }
}

// -------------------- CSR build, pass A: LDS-presorted slotted scatter --------------------
// Block counting-sorts its 3072 edges by bucket in LDS, reserves global ranges
// (one padded atomic per touched bucket), writes each bucket's run contiguously.
// gcnt (stride GPAD) ends as final bucket counts. LDS: 48 + 6.2 = 54.2 KB.
__global__ __launch_bounds__(256) void bucket_scatter(const int* __restrict__ rows_all,
                                                      const int* __restrict__ cols_all,
                                                      const float* __restrict__ vals_all,
                                                      int* __restrict__ gcnt,
                                                      int2* __restrict__ slots)
{
    const int a = blockIdx.y;
    __shared__ int2 buf[EPB];      // 24 KB
    __shared__ int2 buf2[EPB];     // 24 KB
    __shared__ int lcnt[NB], lscan[NB], lcur[NB], lbase[NB];  // 6.2 KB
    for (int i = threadIdx.x; i < NB; i += 256) lcnt[i] = 0;
    __syncthreads();
    const int e0 = blockIdx.x * EPB;
    const int n = min(EPB, N_EDGES - e0);
    for (int i = threadIdx.x; i < n; i += 256) {
        const size_t idx = (size_t)a * N_EDGES + e0 + i;
        const int r = rows_all[idx];
        int2 pq;
        pq.x = (r << 16) | cols_all[idx];
        pq.y = __float_as_int(vals_all[idx]);
        buf[i] = pq;
        atomicAdd(&lcnt[r >> BSHIFT], 1);
    }
    __syncthreads();
    if (threadIdx.x < 64) {
        const int lane = threadIdx.x;
        int carry = 0;
        #pragma unroll
        for (int c = 0; c < 7; ++c) {
            const int i = c * 64 + lane;
            const int v = (i < NB) ? lcnt[i] : 0;
            int xs = v;
            #pragma unroll
            for (int d = 1; d < 64; d <<= 1) { const int t = __shfl_up(xs, d, 64); if (lane >= d) xs += t; }
            const int excl = carry + xs - v;
            if (i < NB) {
                lscan[i] = excl; lcur[i] = excl;
                lbase[i] = v ? atomicAdd(&gcnt[(a * NB + i) * GPAD], v) : 0;
            }
            carry += __shfl(xs, 63, 64);
        }
    }
    __syncthreads();
    for (int i = threadIdx.x; i < n; i += 256) {
        const int2 p = buf[i];
        const unsigned r = ((unsigned)p.x) >> 16;
        const int pos = atomicAdd(&lcur[r >> BSHIFT], 1);
        buf2[pos] = p;
    }
    __syncthreads();
    for (int i = threadIdx.x; i < n; i += 256) {
        const int2 p = buf2[i];
        const unsigned r = ((unsigned)p.x) >> 16;
        const int b = r >> BSHIFT;
        slots[((size_t)a * NB + b) * SLOTCAP + lbase[b] + (i - lscan[b])] = p;
    }
}

// -------------------- CSR build, pass B: LDS row sort + atomic range reservation --------
// Each (a,bucket) block reserves its output range from a per-adjacency cursor
// (no prefix-scan kernel needed: rows carry explicit start+count).
__global__ __launch_bounds__(256) void build_csr(const int2* __restrict__ slots,
                                                 const int* __restrict__ gcnt,
                                                 int* __restrict__ cursor,
                                                 int* __restrict__ rs_start,
                                                 int* __restrict__ rs_cnt,
                                                 int2* __restrict__ sorted_cv)
{
    const int a = blockIdx.y, b = blockIdx.x;
    const int n = gcnt[(a * NB + b) * GPAD];
    __shared__ int cnt[128], cur[128];
    __shared__ int s_base;
    __shared__ int2 buf[BCAP];    // 22 KB
    __shared__ int2 buf2[BCAP];   // 22 KB
    if (threadIdx.x < 128) cnt[threadIdx.x] = 0;
    if (threadIdx.x == 0) s_base = atomicAdd(&cursor[a * GPAD], n);
    __syncthreads();
    const int2* bk = slots + ((size_t)a * NB + b) * SLOTCAP;
    const bool fits = (n <= BCAP);
    for (int i = threadIdx.x; i < n; i += 256) {
        const int2 p = bk[i];
        if (fits) buf[i] = p;
        atomicAdd(&cnt[(p.x >> 16) & 127], 1);
    }
    __syncthreads();
    const int s = s_base;
    const int lane = threadIdx.x & 63, wid = threadIdx.x >> 6;
    if (wid == 0) {
        const int i0 = lane * 2;
        const int c0 = cnt[i0], c1 = cnt[i0 + 1];
        const int sum = c0 + c1;
        int xs = sum;
        #pragma unroll
        for (int d = 1; d < 64; d <<= 1) { const int t = __shfl_up(xs, d, 64); if (lane >= d) xs += t; }
        const int base = xs - sum;        // exclusive, local to bucket
        const int o0 = base, o1 = base + c0;
        cur[i0] = o0; cur[i0 + 1] = o1;
        int* rsS = rs_start + (size_t)a * N_NODES;
        int* rsC = rs_cnt   + (size_t)a * N_NODES;
        const int gr = (b << BSHIFT) + i0;
        if (gr + 0 < N_NODES) { rsS[gr + 0] = s + o0; rsC[gr + 0] = c0; }
        if (gr + 1 < N_NODES) { rsS[gr + 1] = s + o1; rsC[gr + 1] = c1; }
    }
    __syncthreads();
    int2* sc = sorted_cv + (size_t)a * N_EDGES;
    if (fits) {
        for (int i = threadIdx.x; i < n; i += 256) {
            const int2 p = buf[i];
            const int pos = atomicAdd(&cur[(p.x >> 16) & 127], 1);
            int2 cv; cv.x = p.x & 0xFFFF; cv.y = p.y;
            buf2[pos] = cv;
        }
        __syncthreads();
        for (int i = threadIdx.x; i < n; i += 256)
            sc[s + i] = buf2[i];                    // coalesced streaming write
    } else {
        for (int i = threadIdx.x; i < n; i += 256) {
            const int2 p = bk[i];
            const int pos = atomicAdd(&cur[(p.x >> 16) & 127], 1);
            int2 cv; cv.x = p.x & 0xFFFF; cv.y = p.y;
            sc[s + pos] = cv;
        }
    }
}

// -------------------- pull-mode SpMM over fp16 states, fp32 accumulate --------------------
static __device__ __forceinline__ void gacc(const _Float16* __restrict__ src,
                                            int col, float v, int lane, f32x4& acc)
{
    const h4 g = *(const h4*)(src + (size_t)col * NHID + lane * 4);
    acc[0] += v * (float)g[0];
    acc[1] += v * (float)g[1];
    acc[2] += v * (float)g[2];
    acc[3] += v * (float)g[3];
}

static __device__ __forceinline__ void pull_part(const int* __restrict__ rs_start,
                                                 const int* __restrict__ rs_cnt,
                                                 const int2* __restrict__ sorted_cv,
                                                 int a, const _Float16* __restrict__ src,
                                                 int row, int lane, f32x4& acc)
{
    const int2* cv = sorted_cv + (size_t)a * N_EDGES;
    const int s    = rs_start[(size_t)a * N_NODES + row];
    const int epnd = s + rs_cnt[(size_t)a * N_NODES + row];
    int e = s;
    for (; e + 3 < epnd; e += 4) {
        const int2 p0 = cv[e];
        const int2 p1 = cv[e + 1];
        const int2 p2 = cv[e + 2];
        const int2 p3 = cv[e + 3];
        gacc(src, p0.x, __int_as_float(p0.y), lane, acc);
        gacc(src, p1.x, __int_as_float(p1.y), lane, acc);
        gacc(src, p2.x, __int_as_float(p2.y), lane, acc);
        gacc(src, p3.x, __int_as_float(p3.y), lane, acc);
    }
    for (; e < epnd; ++e) {
        const int2 p0 = cv[e];
        gacc(src, p0.x, __int_as_float(p0.y), lane, acc);
    }
}

template<int PARTS, bool LN>
__global__ __launch_bounds__(256) void pull_spmm(
    const int* __restrict__ rs_start, const int* __restrict__ rs_cnt,
    const int2* __restrict__ sorted_cv,
    const int* __restrict__ idx_a, int pos_a, const _Float16* __restrict__ src_a,
    const int* __restrict__ idx_b, int pos_b, const _Float16* __restrict__ src_b,
    const int* __restrict__ idx_c, int pos_c, const _Float16* __restrict__ src_c,
    _Float16* __restrict__ outh, float* __restrict__ outf,
    const float* __restrict__ gamma, const float* __restrict__ beta)
{
    const int row  = (blockIdx.x * 256 + threadIdx.x) >> 6;
    const int lane = threadIdx.x & 63;
    if (row >= N_NODES) return;
    f32x4 acc = {0.f, 0.f, 0.f, 0.f};
    pull_part(rs_start, rs_cnt, sorted_cv, idx_a[pos_a], src_a, row, lane, acc);
    if constexpr (PARTS >= 2) pull_part(rs_start, rs_cnt, sorted_cv, idx_b[pos_b], src_b, row, lane, acc);
    if constexpr (PARTS >= 3) pull_part(rs_start, rs_cnt, sorted_cv, idx_c[pos_c], src_c, row, lane, acc);

    if constexpr (LN) {
        float sum = acc[0] + acc[1] + acc[2] + acc[3];
        float sq  = acc[0] * acc[0] + acc[1] * acc[1] + acc[2] * acc[2] + acc[3] * acc[3];
        #pragma unroll
        for (int off = 1; off < 64; off <<= 1) {
            sum += __shfl_xor(sum, off, 64);
            sq  += __shfl_xor(sq,  off, 64);
        }
        const float mu   = sum * (1.f / NHID);
        const float var  = sq * (1.f / NHID) - mu * mu;
        const float rstd = rsqrtf(var + LN_EPS);
        const float4 g4 = *(const float4*)(gamma + lane * 4);
        const float4 b4 = *(const float4*)(beta + lane * 4);
        const float g[4]  = {g4.x, g4.y, g4.z, g4.w};
        const float bb[4] = {b4.x, b4.y, b4.z, b4.w};
        f32x4 o;
        #pragma unroll
        for (int j = 0; j < 4; ++j) {
            const float y = (acc[j] - mu) * rstd * g[j] + bb[j];
            o[j] = 0.5f * y * (1.f + erff(y * 0.70710678118654752f));
        }
        __builtin_nontemporal_store(o, (f32x4*)(outf + (size_t)row * NHID + lane * 4));
    } else {
        h4 o;
        o[0] = (_Float16)acc[0]; o[1] = (_Float16)acc[1];
        o[2] = (_Float16)acc[2]; o[3] = (_Float16)acc[3];
        __builtin_nontemporal_store(o, (h4*)(outh + (size_t)row * NHID + lane * 4));
    }
}

extern "C" void kernel_launch(void* const* d_in, const int* in_sizes, int n_in,
                              void* d_out, int out_size, void* d_ws, size_t ws_size,
                              hipStream_t stream)
{
    (void)in_sizes; (void)n_in; (void)out_size; (void)ws_size;
    const float* x        = (const float*)d_in[0];
    const int* adj_rows   = (const int*)d_in[1];
    const int* adj_cols   = (const int*)d_in[2];
    const float* vals     = (const float*)d_in[3];
    const int* idx_seq    = (const int*)d_in[4];
    const int* idx_res    = (const int*)d_in[5];
    const float* W        = (const float*)d_in[6];
    const float* bias     = (const float*)d_in[7];
    const float* gam      = (const float*)d_in[8];
    const float* bet      = (const float*)d_in[9];

    const size_t S = (size_t)N_NODES * NHID;
    _Float16* s0 = (_Float16*)d_ws;            // 25.6 MB each
    _Float16* s1 = s0 + S;
    _Float16* s2 = s1 + S;
    int2*  sorted_cv      = (int2*)(s2 + S);                                  // 38.4 MB
    int*   rs_start       = (int*)(sorted_cv + (size_t)N_ADJS * N_EDGES);     // 1.2 MB
    int*   rs_cnt         = rs_start + (size_t)N_ADJS * N_NODES;              // 1.2 MB
    _Float16* Wh          = (_Float16*)(rs_cnt + (size_t)N_ADJS * N_NODES);   // 128 KB
    int*   gcnt           = (int*)(Wh + NHID * NHID);                         // 150 KB (padded)
    int*   cursor         = gcnt + N_ADJS * NB * GPAD;                        // 384 B (padded)
    // slots alias s1+s2: 6*391*2560*8 = 48.0 MB <= 51.2 MB; dead before pull1 writes s1.
    int2*  slots          = (int2*)s1;

    convert_w<<<dim3(NHID * NHID / 256), dim3(256), 0, stream>>>(W, Wh, gcnt, cursor);
    gemm_mfma<<<dim3((N_NODES + 63) / 64), dim3(256), 0, stream>>>(x, Wh, bias, s0);

    const int eblocks = (N_EDGES + EPB - 1) / EPB;
    bucket_scatter<<<dim3(eblocks, N_ADJS), dim3(256), 0, stream>>>(adj_rows, adj_cols, vals, gcnt, slots);
    build_csr<<<dim3(NB, N_ADJS), dim3(256), 0, stream>>>(slots, gcnt, cursor, rs_start, rs_cnt, sorted_cv);

    const dim3 pgrid(N_NODES * 64 / 256);
    pull_spmm<1, false><<<pgrid, dim3(256), 0, stream>>>(rs_start, rs_cnt, sorted_cv,
        idx_seq, 0, s0,  nullptr, 0, nullptr,  nullptr, 0, nullptr,
        s1, nullptr, nullptr, nullptr);
    pull_spmm<2, false><<<pgrid, dim3(256), 0, stream>>>(rs_start, rs_cnt, sorted_cv,
        idx_seq, 1, s1,  idx_res, 0, s0,  nullptr, 0, nullptr,
        s2, nullptr, nullptr, nullptr);
    pull_spmm<3, true><<<pgrid, dim3(256), 0, stream>>>(rs_start, rs_cnt, sorted_cv,
        idx_seq, 2, s2,  idx_res, 1, s0,  idx_res, 2, s1,
        nullptr, (float*)d_out, gam, bet);
}

// Round 9
// 631.099 us; speedup vs baseline: 1.0788x; 1.0653x over previous
//
#include <hip/hip_runtime.h>
#include <math.h>

#define N_NODES 50000
#define N_EDGES 800000
#define N_ADJS  6
#define NHID    256
#define BSHIFT  7         // 128-row buckets
#define NB      391       // ceil(50000/128)
#define SLOTCAP 2560      // fixed slot capacity per bucket (mean fill ~2046, max ~2250)
#define BCAP    2816      // LDS sort capacity in build_csr
#define LN_EPS  1e-5f

typedef _Float16 f16x8 __attribute__((ext_vector_type(8)));
typedef float f32x4  __attribute__((ext_vector_type(4)));
typedef _Float16 h4  __attribute__((ext_vector_type(4)));   // 8-byte fp16 quad

// -------------------- W -> fp16 (+ compute used-adjacency flags) --------------------
__global__ __launch_bounds__(256) void convert_w(const float* __restrict__ W,
                                                 _Float16* __restrict__ Wh,
                                                 const int* __restrict__ idx_seq,
                                                 const int* __restrict__ idx_res,
                                                 int* __restrict__ used)
{
    const int i = blockIdx.x * 256 + threadIdx.x;   // 65536 total
    Wh[i] = (_Float16)W[i];
    if (blockIdx.x == 0 && threadIdx.x < N_ADJS) {
        const int a = threadIdx.x;
        int u = 0;
        #pragma unroll
        for (int j = 0; j < 3; ++j) u |= (idx_seq[j] == a) | (idx_res[j] == a);
        used[a] = u;
    }
}

// -------------------- h = x @ W^T + b via MFMA (fp16 in, fp32 acc) --------------------
__global__ __launch_bounds__(256) void gemm_mfma(const float* __restrict__ x,
                                                 const _Float16* __restrict__ Wh,
                                                 const float* __restrict__ bias,
                                                 _Float16* __restrict__ h)
{
    const int tid = threadIdx.x;
    const int w = tid >> 6, l = tid & 63;
    const int m = l & 15, q = l >> 4;
    const int row0 = blockIdx.x * 64 + w * 16;
    const int arow = row0 + m;
    const int arow_c = (arow < N_NODES) ? arow : 0;

    f32x4 acc[16];
    #pragma unroll
    for (int nt = 0; nt < 16; ++nt) acc[nt] = (f32x4){0.f, 0.f, 0.f, 0.f};

    for (int kt = 0; kt < NHID; kt += 32) {
        const float* xp = x + (size_t)arow_c * NHID + kt + q * 8;
        const float4 xa = *(const float4*)xp;
        const float4 xb = *(const float4*)(xp + 4);
        f16x8 ah;
        ah[0] = (_Float16)xa.x; ah[1] = (_Float16)xa.y;
        ah[2] = (_Float16)xa.z; ah[3] = (_Float16)xa.w;
        ah[4] = (_Float16)xb.x; ah[5] = (_Float16)xb.y;
        ah[6] = (_Float16)xb.z; ah[7] = (_Float16)xb.w;
        const int ko = kt + q * 8;
        #pragma unroll
        for (int nt = 0; nt < 16; ++nt) {
            const size_t off = (size_t)(nt * 16 + m) * NHID + ko;
            const f16x8 bh = *(const f16x8*)(Wh + off);
            acc[nt] = __builtin_amdgcn_mfma_f32_16x16x32_f16(ah, bh, acc[nt], 0, 0, 0);
        }
    }

    // C/D: col = lane&15, row = (lane>>4)*4 + reg
    #pragma unroll
    for (int nt = 0; nt < 16; ++nt) {
        const int col = nt * 16 + m;
        const float bv = bias[col];
        #pragma unroll
        for (int r = 0; r < 4; ++r) {
            const int grow = row0 + q * 4 + r;
            if (grow < N_NODES) h[(size_t)grow * NHID + col] = (_Float16)(acc[nt][r] + bv);
        }
    }
}

// -------------------- CSR build, pass A: slotted scatter (4096 edges/block) --------------------
// Skips unused adjacencies. Per-block LDS aggregation reserves ranges in
// fixed-capacity slots via atomicAdd on zero-initialized gcnt.
__global__ __launch_bounds__(256) void bucket_scatter(const int* __restrict__ rows_all,
                                                      const int* __restrict__ cols_all,
                                                      const float* __restrict__ vals_all,
                                                      int* __restrict__ gcnt,
                                                      int2* __restrict__ slots,
                                                      const int* __restrict__ used)
{
    const int a = blockIdx.y;
    if (!used[a]) return;
    __shared__ int lcnt[NB], lbase[NB];
    for (int i = threadIdx.x; i < NB; i += 256) lcnt[i] = 0;
    __syncthreads();
    int bq[16], sq[16]; int2 pq[16];
    const int e0 = blockIdx.x * 4096 + threadIdx.x;
    #pragma unroll
    for (int j = 0; j < 16; ++j) {
        const int e = e0 + j * 256;
        bq[j] = -1;
        if (e < N_EDGES) {
            const size_t idx = (size_t)a * N_EDGES + e;
            const int r = rows_all[idx];
            const int b = r >> BSHIFT;
            bq[j] = b;
            sq[j] = atomicAdd(&lcnt[b], 1);
            pq[j].x = (r << 16) | cols_all[idx];
            pq[j].y = __float_as_int(vals_all[idx]);
        }
    }
    __syncthreads();
    for (int i = threadIdx.x; i < NB; i += 256)
        lbase[i] = lcnt[i] ? atomicAdd(&gcnt[a * NB + i], lcnt[i]) : 0;
    __syncthreads();
    #pragma unroll
    for (int j = 0; j < 16; ++j)
        if (bq[j] >= 0)
            slots[((size_t)a * NB + bq[j]) * SLOTCAP + lbase[bq[j]] + sq[j]] = pq[j];
}

// -------------------- CSR build: scan final counts -> compacted bstart --------------------
__global__ __launch_bounds__(384) void scan_buckets(const int* __restrict__ gcnt,
                                                    int* __restrict__ bstart,
                                                    int* __restrict__ row_start)
{
    const int lane = threadIdx.x & 63, a = threadIdx.x >> 6;
    if (a >= N_ADJS) return;
    int carry = 0;
    #pragma unroll
    for (int c = 0; c < 7; ++c) {
        const int i = c * 64 + lane;
        const int v = (i < NB) ? gcnt[a * NB + i] : 0;
        int xs = v;
        #pragma unroll
        for (int d = 1; d < 64; d <<= 1) { const int t = __shfl_up(xs, d, 64); if (lane >= d) xs += t; }
        const int excl = carry + xs - v;
        if (i < NB) bstart[a * (NB + 1) + i] = excl;
        carry += __shfl(xs, 63, 64);
    }
    if (lane == 0) {
        bstart[a * (NB + 1) + NB] = N_EDGES;
        row_start[(size_t)a * (N_NODES + 1) + N_NODES] = N_EDGES;
    }
}

// -------------------- CSR build, pass B: LDS-staged per-bucket row sort --------------------
// Skips unused adjacencies. Reads slotted bucket, histograms, rank-scatters in
// LDS, writes compacted+coalesced.
__global__ __launch_bounds__(256) void build_csr(const int2* __restrict__ slots,
                                                 const int* __restrict__ bstart,
                                                 int* __restrict__ row_start,
                                                 int2* __restrict__ sorted_cv,
                                                 const int* __restrict__ used)
{
    const int a = blockIdx.y, b = blockIdx.x;
    if (!used[a]) return;
    const int s = bstart[a * (NB + 1) + b];
    const int n = bstart[a * (NB + 1) + b + 1] - s;
    __shared__ int cnt[128], cur[128];
    __shared__ int2 buf[BCAP];    // 22 KB
    __shared__ int2 buf2[BCAP];   // 22 KB
    if (threadIdx.x < 128) cnt[threadIdx.x] = 0;
    __syncthreads();
    const int2* bk = slots + ((size_t)a * NB + b) * SLOTCAP;
    const bool fits = (n <= BCAP);
    for (int i = threadIdx.x; i < n; i += 256) {
        const int2 p = bk[i];
        if (fits) buf[i] = p;
        atomicAdd(&cnt[(p.x >> 16) & 127], 1);
    }
    __syncthreads();
    const int lane = threadIdx.x & 63, wid = threadIdx.x >> 6;
    if (wid == 0) {
        const int i0 = lane * 2;
        const int c0 = cnt[i0], c1 = cnt[i0 + 1];
        const int sum = c0 + c1;
        int xs = sum;
        #pragma unroll
        for (int d = 1; d < 64; d <<= 1) { const int t = __shfl_up(xs, d, 64); if (lane >= d) xs += t; }
        const int base = xs - sum;        // exclusive, local to bucket
        const int o0 = base, o1 = base + c0;
        cur[i0] = o0; cur[i0 + 1] = o1;
        int* rs = row_start + (size_t)a * (N_NODES + 1);
        const int gr = (b << BSHIFT) + i0;
        if (gr + 0 < N_NODES) rs[gr + 0] = s + o0;
        if (gr + 1 < N_NODES) rs[gr + 1] = s + o1;
    }
    __syncthreads();
    int2* sc = sorted_cv + (size_t)a * N_EDGES;
    if (fits) {
        for (int i = threadIdx.x; i < n; i += 256) {
            const int2 p = buf[i];
            const int pos = atomicAdd(&cur[(p.x >> 16) & 127], 1);
            int2 cv; cv.x = p.x & 0xFFFF; cv.y = p.y;
            buf2[pos] = cv;
        }
        __syncthreads();
        for (int i = threadIdx.x; i < n; i += 256)
            sc[s + i] = buf2[i];                    // coalesced streaming write
    } else {
        for (int i = threadIdx.x; i < n; i += 256) {
            const int2 p = bk[i];
            const int pos = atomicAdd(&cur[(p.x >> 16) & 127], 1);
            int2 cv; cv.x = p.x & 0xFFFF; cv.y = p.y;
            sc[s + pos] = cv;
        }
    }
}

// -------------------- pull-mode SpMM over fp16 states, fp32 accumulate --------------------
static __device__ __forceinline__ void gacc(const _Float16* __restrict__ src,
                                            int col, float v, int lane, f32x4& acc)
{
    const h4 g = *(const h4*)(src + (size_t)col * NHID + lane * 4);
    acc[0] += v * (float)g[0];
    acc[1] += v * (float)g[1];
    acc[2] += v * (float)g[2];
    acc[3] += v * (float)g[3];
}

static __device__ __forceinline__ void pull_part(const int* __restrict__ row_start,
                                                 const int2* __restrict__ sorted_cv,
                                                 int a, const _Float16* __restrict__ src,
                                                 int row, int lane, f32x4& acc)
{
    const int2* cv = sorted_cv + (size_t)a * N_EDGES;
    const int* rs  = row_start + (size_t)a * (N_NODES + 1);
    const int s = rs[row], epnd = rs[row + 1];
    int e = s;
    for (; e + 3 < epnd; e += 4) {
        const int2 p0 = cv[e];
        const int2 p1 = cv[e + 1];
        const int2 p2 = cv[e + 2];
        const int2 p3 = cv[e + 3];
        gacc(src, p0.x, __int_as_float(p0.y), lane, acc);
        gacc(src, p1.x, __int_as_float(p1.y), lane, acc);
        gacc(src, p2.x, __int_as_float(p2.y), lane, acc);
        gacc(src, p3.x, __int_as_float(p3.y), lane, acc);
    }
    for (; e < epnd; ++e) {
        const int2 p0 = cv[e];
        gacc(src, p0.x, __int_as_float(p0.y), lane, acc);
    }
}

template<int PARTS, bool LN>
__global__ __launch_bounds__(256) void pull_spmm(
    const int* __restrict__ row_start, const int2* __restrict__ sorted_cv,
    const int* __restrict__ idx_a, int pos_a, const _Float16* __restrict__ src_a,
    const int* __restrict__ idx_b, int pos_b, const _Float16* __restrict__ src_b,
    const int* __restrict__ idx_c, int pos_c, const _Float16* __restrict__ src_c,
    _Float16* __restrict__ outh, float* __restrict__ outf,
    const float* __restrict__ gamma, const float* __restrict__ beta)
{
    const int row  = (blockIdx.x * 256 + threadIdx.x) >> 6;
    const int lane = threadIdx.x & 63;
    if (row >= N_NODES) return;
    f32x4 acc = {0.f, 0.f, 0.f, 0.f};
    pull_part(row_start, sorted_cv, idx_a[pos_a], src_a, row, lane, acc);
    if constexpr (PARTS >= 2) pull_part(row_start, sorted_cv, idx_b[pos_b], src_b, row, lane, acc);
    if constexpr (PARTS >= 3) pull_part(row_start, sorted_cv, idx_c[pos_c], src_c, row, lane, acc);

    if constexpr (LN) {
        float sum = acc[0] + acc[1] + acc[2] + acc[3];
        float sq  = acc[0] * acc[0] + acc[1] * acc[1] + acc[2] * acc[2] + acc[3] * acc[3];
        #pragma unroll
        for (int off = 1; off < 64; off <<= 1) {
            sum += __shfl_xor(sum, off, 64);
            sq  += __shfl_xor(sq,  off, 64);
        }
        const float mu   = sum * (1.f / NHID);
        const float var  = sq * (1.f / NHID) - mu * mu;
        const float rstd = rsqrtf(var + LN_EPS);
        const float4 g4 = *(const float4*)(gamma + lane * 4);
        const float4 b4 = *(const float4*)(beta + lane * 4);
        const float g[4]  = {g4.x, g4.y, g4.z, g4.w};
        const float bb[4] = {b4.x, b4.y, b4.z, b4.w};
        f32x4 o;
        #pragma unroll
        for (int j = 0; j < 4; ++j) {
            const float y = (acc[j] - mu) * rstd * g[j] + bb[j];
            o[j] = 0.5f * y * (1.f + erff(y * 0.70710678118654752f));
        }
        __builtin_nontemporal_store(o, (f32x4*)(outf + (size_t)row * NHID + lane * 4));
    } else {
        h4 o;
        o[0] = (_Float16)acc[0]; o[1] = (_Float16)acc[1];
        o[2] = (_Float16)acc[2]; o[3] = (_Float16)acc[3];
        __builtin_nontemporal_store(o, (h4*)(outh + (size_t)row * NHID + lane * 4));
    }
}

extern "C" void kernel_launch(void* const* d_in, const int* in_sizes, int n_in,
                              void* d_out, int out_size, void* d_ws, size_t ws_size,
                              hipStream_t stream)
{
    (void)in_sizes; (void)n_in; (void)out_size; (void)ws_size;
    const float* x        = (const float*)d_in[0];
    const int* adj_rows   = (const int*)d_in[1];
    const int* adj_cols   = (const int*)d_in[2];
    const float* vals     = (const float*)d_in[3];
    const int* idx_seq    = (const int*)d_in[4];
    const int* idx_res    = (const int*)d_in[5];
    const float* W        = (const float*)d_in[6];
    const float* bias     = (const float*)d_in[7];
    const float* gam      = (const float*)d_in[8];
    const float* bet      = (const float*)d_in[9];

    const size_t S = (size_t)N_NODES * NHID;
    _Float16* s0 = (_Float16*)d_ws;            // 25.6 MB each
    _Float16* s1 = s0 + S;
    _Float16* s2 = s1 + S;
    int2*  sorted_cv      = (int2*)(s2 + S);                                  // 38.4 MB
    int*   row_start      = (int*)(sorted_cv + (size_t)N_ADJS * N_EDGES);     // 1.2 MB
    _Float16* Wh          = (_Float16*)(row_start + (size_t)N_ADJS * (N_NODES + 1)); // 128 KB
    int*   gcnt           = (int*)(Wh + NHID * NHID);
    int*   bstart         = gcnt + N_ADJS * NB;
    int*   used           = bstart + N_ADJS * (NB + 1);
    // slots alias s1+s2: 6*391*2560*8 = 48.0 MB <= 51.2 MB; dead before pull1 writes s1.
    int2*  slots          = (int2*)s1;

    hipMemsetAsync(gcnt, 0, (size_t)N_ADJS * NB * sizeof(int), stream);

    convert_w<<<dim3(NHID * NHID / 256), dim3(256), 0, stream>>>(W, Wh, idx_seq, idx_res, used);
    gemm_mfma<<<dim3((N_NODES + 63) / 64), dim3(256), 0, stream>>>(x, Wh, bias, s0);

    const int eblocks = (N_EDGES + 4095) / 4096;
    bucket_scatter<<<dim3(eblocks, N_ADJS), dim3(256), 0, stream>>>(adj_rows, adj_cols, vals, gcnt, slots, used);
    scan_buckets<<<dim3(1), dim3(384), 0, stream>>>(gcnt, bstart, row_start);
    build_csr<<<dim3(NB, N_ADJS), dim3(256), 0, stream>>>(slots, bstart, row_start, sorted_cv, used);

    const dim3 pgrid(N_NODES * 64 / 256);
    pull_spmm<1, false><<<pgrid, dim3(256), 0, stream>>>(row_start, sorted_cv,
        idx_seq, 0, s0,  nullptr, 0, nullptr,  nullptr, 0, nullptr,
        s1, nullptr, nullptr, nullptr);
    pull_spmm<2, false><<<pgrid, dim3(256), 0, stream>>>(row_start, sorted_cv,
        idx_seq, 1, s1,  idx_res, 0, s0,  nullptr, 0, nullptr,
        s2, nullptr, nullptr, nullptr);
    pull_spmm<3, true><<<pgrid, dim3(256), 0, stream>>>(row_start, sorted_cv,
        idx_seq, 2, s2,  idx_res, 1, s0,  idx_res, 2, s1,
        nullptr, (float*)d_out, gam, bet);
}

// Round 10
// 612.374 us; speedup vs baseline: 1.1118x; 1.0306x over previous
//
#include <hip/hip_runtime.h>
#include <math.h>

#define N_NODES 50000
#define N_EDGES 800000
#define N_ADJS  6
#define NHID    256
#define BSHIFT  7         // 128-row buckets
#define NB      391       // ceil(50000/128)
#define SLOTCAP 2560      // fixed slot capacity per bucket (mean fill ~2046, max ~2250)
#define BCAP    2816      // LDS sort capacity in build_csr
#define LN_EPS  1e-5f

typedef _Float16 f16x8 __attribute__((ext_vector_type(8)));
typedef float f32x4  __attribute__((ext_vector_type(4)));
typedef _Float16 h4  __attribute__((ext_vector_type(4)));   // 8-byte fp16 quad

union h16cast { unsigned short u; _Float16 h; };

// -------------------- W -> fp16 (+ zero gcnt, compute used-adjacency flags) --------------------
__global__ __launch_bounds__(256) void convert_w(const float* __restrict__ W,
                                                 _Float16* __restrict__ Wh,
                                                 const int* __restrict__ idx_seq,
                                                 const int* __restrict__ idx_res,
                                                 int* __restrict__ used,
                                                 int* __restrict__ gcnt)
{
    const int i = blockIdx.x * 256 + threadIdx.x;   // 65536 total
    Wh[i] = (_Float16)W[i];
    if (i < N_ADJS * NB) gcnt[i] = 0;
    if (blockIdx.x == 0 && threadIdx.x < N_ADJS) {
        const int a = threadIdx.x;
        int u = 0;
        #pragma unroll
        for (int j = 0; j < 3; ++j) u |= (idx_seq[j] == a) | (idx_res[j] == a);
        used[a] = u;
    }
}

// -------------------- h = x @ W^T + b via MFMA (fp16 in, fp32 acc) --------------------
__global__ __launch_bounds__(256) void gemm_mfma(const float* __restrict__ x,
                                                 const _Float16* __restrict__ Wh,
                                                 const float* __restrict__ bias,
                                                 _Float16* __restrict__ h)
{
    const int tid = threadIdx.x;
    const int w = tid >> 6, l = tid & 63;
    const int m = l & 15, q = l >> 4;
    const int row0 = blockIdx.x * 64 + w * 16;
    const int arow = row0 + m;
    const int arow_c = (arow < N_NODES) ? arow : 0;

    f32x4 acc[16];
    #pragma unroll
    for (int nt = 0; nt < 16; ++nt) acc[nt] = (f32x4){0.f, 0.f, 0.f, 0.f};

    for (int kt = 0; kt < NHID; kt += 32) {
        const float* xp = x + (size_t)arow_c * NHID + kt + q * 8;
        const float4 xa = *(const float4*)xp;
        const float4 xb = *(const float4*)(xp + 4);
        f16x8 ah;
        ah[0] = (_Float16)xa.x; ah[1] = (_Float16)xa.y;
        ah[2] = (_Float16)xa.z; ah[3] = (_Float16)xa.w;
        ah[4] = (_Float16)xb.x; ah[5] = (_Float16)xb.y;
        ah[6] = (_Float16)xb.z; ah[7] = (_Float16)xb.w;
        const int ko = kt + q * 8;
        #pragma unroll
        for (int nt = 0; nt < 16; ++nt) {
            const size_t off = (size_t)(nt * 16 + m) * NHID + ko;
            const f16x8 bh = *(const f16x8*)(Wh + off);
            acc[nt] = __builtin_amdgcn_mfma_f32_16x16x32_f16(ah, bh, acc[nt], 0, 0, 0);
        }
    }

    // C/D: col = lane&15, row = (lane>>4)*4 + reg
    #pragma unroll
    for (int nt = 0; nt < 16; ++nt) {
        const int col = nt * 16 + m;
        const float bv = bias[col];
        #pragma unroll
        for (int r = 0; r < 4; ++r) {
            const int grow = row0 + q * 4 + r;
            if (grow < N_NODES) h[(size_t)grow * NHID + col] = (_Float16)(acc[nt][r] + bv);
        }
    }
}

// -------------------- CSR build, pass A: slotted scatter (4096 edges/block) --------------------
// Skips unused adjacencies. Per-block LDS aggregation reserves ranges in
// fixed-capacity slots via atomicAdd on zero-initialized gcnt.
__global__ __launch_bounds__(256) void bucket_scatter(const int* __restrict__ rows_all,
                                                      const int* __restrict__ cols_all,
                                                      const float* __restrict__ vals_all,
                                                      int* __restrict__ gcnt,
                                                      int2* __restrict__ slots,
                                                      const int* __restrict__ used)
{
    const int a = blockIdx.y;
    if (!used[a]) return;
    __shared__ int lcnt[NB], lbase[NB];
    for (int i = threadIdx.x; i < NB; i += 256) lcnt[i] = 0;
    __syncthreads();
    int bq[16], sq[16]; int2 pq[16];
    const int e0 = blockIdx.x * 4096 + threadIdx.x;
    #pragma unroll
    for (int j = 0; j < 16; ++j) {
        const int e = e0 + j * 256;
        bq[j] = -1;
        if (e < N_EDGES) {
            const size_t idx = (size_t)a * N_EDGES + e;
            const int r = rows_all[idx];
            const int b = r >> BSHIFT;
            bq[j] = b;
            sq[j] = atomicAdd(&lcnt[b], 1);
            pq[j].x = (r << 16) | cols_all[idx];
            pq[j].y = __float_as_int(vals_all[idx]);
        }
    }
    __syncthreads();
    for (int i = threadIdx.x; i < NB; i += 256)
        lbase[i] = lcnt[i] ? atomicAdd(&gcnt[a * NB + i], lcnt[i]) : 0;
    __syncthreads();
    #pragma unroll
    for (int j = 0; j < 16; ++j)
        if (bq[j] >= 0)
            slots[((size_t)a * NB + bq[j]) * SLOTCAP + lbase[bq[j]] + sq[j]] = pq[j];
}

// -------------------- CSR build: scan final counts -> compacted bstart --------------------
__global__ __launch_bounds__(384) void scan_buckets(const int* __restrict__ gcnt,
                                                    int* __restrict__ bstart,
                                                    int* __restrict__ row_start)
{
    const int lane = threadIdx.x & 63, a = threadIdx.x >> 6;
    if (a >= N_ADJS) return;
    int carry = 0;
    #pragma unroll
    for (int c = 0; c < 7; ++c) {
        const int i = c * 64 + lane;
        const int v = (i < NB) ? gcnt[a * NB + i] : 0;
        int xs = v;
        #pragma unroll
        for (int d = 1; d < 64; d <<= 1) { const int t = __shfl_up(xs, d, 64); if (lane >= d) xs += t; }
        const int excl = carry + xs - v;
        if (i < NB) bstart[a * (NB + 1) + i] = excl;
        carry += __shfl(xs, 63, 64);
    }
    if (lane == 0) {
        bstart[a * (NB + 1) + NB] = N_EDGES;
        row_start[(size_t)a * (N_NODES + 1) + N_NODES] = N_EDGES;
    }
}

// -------------------- CSR build, pass B: LDS-staged per-bucket row sort --------------------
// Skips unused adjacencies. Output compressed to 4B/edge: (fp16(val)<<16) | col.
__global__ __launch_bounds__(256) void build_csr(const int2* __restrict__ slots,
                                                 const int* __restrict__ bstart,
                                                 int* __restrict__ row_start,
                                                 unsigned* __restrict__ sorted_cv,
                                                 const int* __restrict__ used)
{
    const int a = blockIdx.y, b = blockIdx.x;
    if (!used[a]) return;
    const int s = bstart[a * (NB + 1) + b];
    const int n = bstart[a * (NB + 1) + b + 1] - s;
    __shared__ int cnt[128], cur[128];
    __shared__ int2 buf[BCAP];       // 22 KB
    __shared__ unsigned buf2[BCAP];  // 11 KB
    if (threadIdx.x < 128) cnt[threadIdx.x] = 0;
    __syncthreads();
    const int2* bk = slots + ((size_t)a * NB + b) * SLOTCAP;
    const bool fits = (n <= BCAP);
    for (int i = threadIdx.x; i < n; i += 256) {
        const int2 p = bk[i];
        if (fits) buf[i] = p;
        atomicAdd(&cnt[(p.x >> 16) & 127], 1);
    }
    __syncthreads();
    const int lane = threadIdx.x & 63, wid = threadIdx.x >> 6;
    if (wid == 0) {
        const int i0 = lane * 2;
        const int c0 = cnt[i0], c1 = cnt[i0 + 1];
        const int sum = c0 + c1;
        int xs = sum;
        #pragma unroll
        for (int d = 1; d < 64; d <<= 1) { const int t = __shfl_up(xs, d, 64); if (lane >= d) xs += t; }
        const int base = xs - sum;        // exclusive, local to bucket
        const int o0 = base, o1 = base + c0;
        cur[i0] = o0; cur[i0 + 1] = o1;
        int* rs = row_start + (size_t)a * (N_NODES + 1);
        const int gr = (b << BSHIFT) + i0;
        if (gr + 0 < N_NODES) rs[gr + 0] = s + o0;
        if (gr + 1 < N_NODES) rs[gr + 1] = s + o1;
    }
    __syncthreads();
    unsigned* sc = sorted_cv + (size_t)a * N_EDGES;
    if (fits) {
        for (int i = threadIdx.x; i < n; i += 256) {
            const int2 p = buf[i];
            const int pos = atomicAdd(&cur[(p.x >> 16) & 127], 1);
            h16cast c16; c16.h = (_Float16)__int_as_float(p.y);
            buf2[pos] = ((unsigned)c16.u << 16) | (unsigned)(p.x & 0xFFFF);
        }
        __syncthreads();
        for (int i = threadIdx.x; i < n; i += 256)
            sc[s + i] = buf2[i];                    // coalesced streaming write
    } else {
        for (int i = threadIdx.x; i < n; i += 256) {
            const int2 p = bk[i];
            const int pos = atomicAdd(&cur[(p.x >> 16) & 127], 1);
            h16cast c16; c16.h = (_Float16)__int_as_float(p.y);
            sc[s + pos] = ((unsigned)c16.u << 16) | (unsigned)(p.x & 0xFFFF);
        }
    }
}

// -------------------- pull-mode SpMM over fp16 states, fp32 accumulate --------------------
static __device__ __forceinline__ void gacc(const _Float16* __restrict__ src,
                                            unsigned cvw, int lane, f32x4& acc)
{
    const int col = (int)(cvw & 0xFFFFu);
    h16cast c16; c16.u = (unsigned short)(cvw >> 16);
    const float v = (float)c16.h;
    const h4 g = *(const h4*)(src + (size_t)col * NHID + lane * 4);
    acc[0] += v * (float)g[0];
    acc[1] += v * (float)g[1];
    acc[2] += v * (float)g[2];
    acc[3] += v * (float)g[3];
}

static __device__ __forceinline__ void pull_part(const int* __restrict__ row_start,
                                                 const unsigned* __restrict__ sorted_cv,
                                                 int a, const _Float16* __restrict__ src,
                                                 int row, int lane, f32x4& acc)
{
    const unsigned* cv = sorted_cv + (size_t)a * N_EDGES;
    const int* rs  = row_start + (size_t)a * (N_NODES + 1);
    const int s = rs[row], epnd = rs[row + 1];
    int e = s;
    for (; e + 3 < epnd; e += 4) {
        const unsigned u0 = cv[e];
        const unsigned u1 = cv[e + 1];
        const unsigned u2 = cv[e + 2];
        const unsigned u3 = cv[e + 3];
        gacc(src, u0, lane, acc);
        gacc(src, u1, lane, acc);
        gacc(src, u2, lane, acc);
        gacc(src, u3, lane, acc);
    }
    for (; e < epnd; ++e) {
        gacc(src, cv[e], lane, acc);
    }
}

template<int PARTS, bool LN>
__global__ __launch_bounds__(256) void pull_spmm(
    const int* __restrict__ row_start, const unsigned* __restrict__ sorted_cv,
    const int* __restrict__ idx_a, int pos_a, const _Float16* __restrict__ src_a,
    const int* __restrict__ idx_b, int pos_b, const _Float16* __restrict__ src_b,
    const int* __restrict__ idx_c, int pos_c, const _Float16* __restrict__ src_c,
    _Float16* __restrict__ outh, float* __restrict__ outf,
    const float* __restrict__ gamma, const float* __restrict__ beta)
{
    const int row  = (blockIdx.x * 256 + threadIdx.x) >> 6;
    const int lane = threadIdx.x & 63;
    if (row >= N_NODES) return;
    f32x4 acc = {0.f, 0.f, 0.f, 0.f};
    pull_part(row_start, sorted_cv, idx_a[pos_a], src_a, row, lane, acc);
    if constexpr (PARTS >= 2) pull_part(row_start, sorted_cv, idx_b[pos_b], src_b, row, lane, acc);
    if constexpr (PARTS >= 3) pull_part(row_start, sorted_cv, idx_c[pos_c], src_c, row, lane, acc);

    if constexpr (LN) {
        float sum = acc[0] + acc[1] + acc[2] + acc[3];
        float sq  = acc[0] * acc[0] + acc[1] * acc[1] + acc[2] * acc[2] + acc[3] * acc[3];
        #pragma unroll
        for (int off = 1; off < 64; off <<= 1) {
            sum += __shfl_xor(sum, off, 64);
            sq  += __shfl_xor(sq,  off, 64);
        }
        const float mu   = sum * (1.f / NHID);
        const float var  = sq * (1.f / NHID) - mu * mu;
        const float rstd = rsqrtf(var + LN_EPS);
        const float4 g4 = *(const float4*)(gamma + lane * 4);
        const float4 b4 = *(const float4*)(beta + lane * 4);
        const float g[4]  = {g4.x, g4.y, g4.z, g4.w};
        const float bb[4] = {b4.x, b4.y, b4.z, b4.w};
        f32x4 o;
        #pragma unroll
        for (int j = 0; j < 4; ++j) {
            const float y = (acc[j] - mu) * rstd * g[j] + bb[j];
            o[j] = 0.5f * y * (1.f + erff(y * 0.70710678118654752f));
        }
        __builtin_nontemporal_store(o, (f32x4*)(outf + (size_t)row * NHID + lane * 4));
    } else {
        h4 o;
        o[0] = (_Float16)acc[0]; o[1] = (_Float16)acc[1];
        o[2] = (_Float16)acc[2]; o[3] = (_Float16)acc[3];
        __builtin_nontemporal_store(o, (h4*)(outh + (size_t)row * NHID + lane * 4));
    }
}

extern "C" void kernel_launch(void* const* d_in, const int* in_sizes, int n_in,
                              void* d_out, int out_size, void* d_ws, size_t ws_size,
                              hipStream_t stream)
{
    (void)in_sizes; (void)n_in; (void)out_size; (void)ws_size;
    const float* x        = (const float*)d_in[0];
    const int* adj_rows   = (const int*)d_in[1];
    const int* adj_cols   = (const int*)d_in[2];
    const float* vals     = (const float*)d_in[3];
    const int* idx_seq    = (const int*)d_in[4];
    const int* idx_res    = (const int*)d_in[5];
    const float* W        = (const float*)d_in[6];
    const float* bias     = (const float*)d_in[7];
    const float* gam      = (const float*)d_in[8];
    const float* bet      = (const float*)d_in[9];

    const size_t S = (size_t)N_NODES * NHID;
    _Float16* s0 = (_Float16*)d_ws;            // 25.6 MB each
    _Float16* s1 = s0 + S;
    _Float16* s2 = s1 + S;
    unsigned* sorted_cv   = (unsigned*)(s2 + S);                              // 19.2 MB
    int*   row_start      = (int*)(sorted_cv + (size_t)N_ADJS * N_EDGES);     // 1.2 MB
    _Float16* Wh          = (_Float16*)(row_start + (size_t)N_ADJS * (N_NODES + 1)); // 128 KB
    int*   gcnt           = (int*)(Wh + NHID * NHID);
    int*   bstart         = gcnt + N_ADJS * NB;
    int*   used           = bstart + N_ADJS * (NB + 1);
    // slots alias s1+s2: 6*391*2560*8 = 48.0 MB <= 51.2 MB; dead before pull1 writes s1.
    int2*  slots          = (int2*)s1;

    convert_w<<<dim3(NHID * NHID / 256), dim3(256), 0, stream>>>(W, Wh, idx_seq, idx_res, used, gcnt);
    gemm_mfma<<<dim3((N_NODES + 63) / 64), dim3(256), 0, stream>>>(x, Wh, bias, s0);

    const int eblocks = (N_EDGES + 4095) / 4096;
    bucket_scatter<<<dim3(eblocks, N_ADJS), dim3(256), 0, stream>>>(adj_rows, adj_cols, vals, gcnt, slots, used);
    scan_buckets<<<dim3(1), dim3(384), 0, stream>>>(gcnt, bstart, row_start);
    build_csr<<<dim3(NB, N_ADJS), dim3(256), 0, stream>>>(slots, bstart, row_start, sorted_cv, used);

    const dim3 pgrid(N_NODES * 64 / 256);
    pull_spmm<1, false><<<pgrid, dim3(256), 0, stream>>>(row_start, sorted_cv,
        idx_seq, 0, s0,  nullptr, 0, nullptr,  nullptr, 0, nullptr,
        s1, nullptr, nullptr, nullptr);
    pull_spmm<2, false><<<pgrid, dim3(256), 0, stream>>>(row_start, sorted_cv,
        idx_seq, 1, s1,  idx_res, 0, s0,  nullptr, 0, nullptr,
        s2, nullptr, nullptr, nullptr);
    pull_spmm<3, true><<<pgrid, dim3(256), 0, stream>>>(row_start, sorted_cv,
        idx_seq, 2, s2,  idx_res, 1, s0,  idx_res, 2, s1,
        nullptr, (float*)d_out, gam, bet);
}

// Round 12
// 600.991 us; speedup vs baseline: 1.1329x; 1.0189x over previous
//
#include <hip/hip_runtime.h>
#include <math.h>

#define N_NODES 50000
#define N_EDGES 800000
#define N_ADJS  6
#define NHID    256
#define BSHIFT  7         // 128-row buckets
#define NB      391       // ceil(50000/128)
#define SLOTCAP 2560      // fixed slot capacity per bucket (mean fill ~2046, max ~2250)
#define BCAP    2816      // LDS sort capacity in build_csr
#define GB      782       // gemm blocks: ceil(50000/64)
#define EB      196       // edge blocks per adjacency: ceil(800000/4096)
#define LN_EPS  1e-5f

typedef _Float16 f16x8 __attribute__((ext_vector_type(8)));
typedef float f32x4  __attribute__((ext_vector_type(4)));
typedef _Float16 h4  __attribute__((ext_vector_type(4)));   // 8-byte fp16 quad

union h16cast { unsigned short u; _Float16 h; };

// -------------------- W -> fp16 (+ zero gcnt, compute used-adjacency flags) --------------------
__global__ __launch_bounds__(256) void convert_w(const float* __restrict__ W,
                                                 _Float16* __restrict__ Wh,
                                                 const int* __restrict__ idx_seq,
                                                 const int* __restrict__ idx_res,
                                                 int* __restrict__ used,
                                                 int* __restrict__ gcnt)
{
    const int i = blockIdx.x * 256 + threadIdx.x;   // 65536 total
    Wh[i] = (_Float16)W[i];
    if (i < N_ADJS * NB) gcnt[i] = 0;
    if (blockIdx.x == 0 && threadIdx.x < N_ADJS) {
        const int a = threadIdx.x;
        int u = 0;
        #pragma unroll
        for (int j = 0; j < 3; ++j) u |= (idx_seq[j] == a) | (idx_res[j] == a);
        used[a] = u;
    }
}

// -------------------- FAT kernel: gemm (blocks 0..GB-1) || bucket_scatter (blocks GB..) ------
// The two chains are independent until pull1; grid-partition fusion overlaps them
// on one stream. Both paths identical to the previously-verified standalone kernels.
__global__ __launch_bounds__(256) void gemm_scatter(
    const float* __restrict__ x, const _Float16* __restrict__ Wh,
    const float* __restrict__ bias, _Float16* __restrict__ h,
    const int* __restrict__ rows_all, const int* __restrict__ cols_all,
    const float* __restrict__ vals_all,
    int* __restrict__ gcnt, int2* __restrict__ slots,
    const int* __restrict__ used)
{
    __shared__ int lcnt[NB], lbase[NB];   // scatter path only (3.1 KB)
    const int bid = blockIdx.x;
    if (bid < GB) {
        // ---------------- gemm path: h = x @ W^T + b via MFMA (fp16 in, fp32 acc) ----------
        const int tid = threadIdx.x;
        const int w = tid >> 6, l = tid & 63;
        const int m = l & 15, q = l >> 4;
        const int row0 = bid * 64 + w * 16;
        const int arow = row0 + m;
        const int arow_c = (arow < N_NODES) ? arow : 0;

        f32x4 acc[16];
        #pragma unroll
        for (int nt = 0; nt < 16; ++nt) acc[nt] = (f32x4){0.f, 0.f, 0.f, 0.f};

        for (int kt = 0; kt < NHID; kt += 32) {
            const float* xp = x + (size_t)arow_c * NHID + kt + q * 8;
            const float4 xa = *(const float4*)xp;
            const float4 xb = *(const float4*)(xp + 4);
            f16x8 ah;
            ah[0] = (_Float16)xa.x; ah[1] = (_Float16)xa.y;
            ah[2] = (_Float16)xa.z; ah[3] = (_Float16)xa.w;
            ah[4] = (_Float16)xb.x; ah[5] = (_Float16)xb.y;
            ah[6] = (_Float16)xb.z; ah[7] = (_Float16)xb.w;
            const int ko = kt + q * 8;
            #pragma unroll
            for (int nt = 0; nt < 16; ++nt) {
                const size_t off = (size_t)(nt * 16 + m) * NHID + ko;
                const f16x8 bh = *(const f16x8*)(Wh + off);
                acc[nt] = __builtin_amdgcn_mfma_f32_16x16x32_f16(ah, bh, acc[nt], 0, 0, 0);
            }
        }

        // C/D: col = lane&15, row = (lane>>4)*4 + reg
        #pragma unroll
        for (int nt = 0; nt < 16; ++nt) {
            const int col = nt * 16 + m;
            const float bv = bias[col];
            #pragma unroll
            for (int r = 0; r < 4; ++r) {
                const int grow = row0 + q * 4 + r;
                if (grow < N_NODES) h[(size_t)grow * NHID + col] = (_Float16)(acc[nt][r] + bv);
            }
        }
    } else {
        // ---------------- scatter path: slotted scatter (4096 edges/block) -----------------
        const int t = bid - GB;
        const int a = t / EB;
        const int eb = t - a * EB;
        if (!used[a]) return;
        for (int i = threadIdx.x; i < NB; i += 256) lcnt[i] = 0;
        __syncthreads();
        int bq[16], sq[16]; int2 pq[16];
        const int e0 = eb * 4096 + threadIdx.x;
        #pragma unroll
        for (int j = 0; j < 16; ++j) {
            const int e = e0 + j * 256;
            bq[j] = -1;
            if (e < N_EDGES) {
                const size_t idx = (size_t)a * N_EDGES + e;
                const int r = rows_all[idx];
                const int b = r >> BSHIFT;
                bq[j] = b;
                sq[j] = atomicAdd(&lcnt[b], 1);
                pq[j].x = (r << 16) | cols_all[idx];
                pq[j].y = __float_as_int(vals_all[idx]);
            }
        }
        __syncthreads();
        for (int i = threadIdx.x; i < NB; i += 256)
            lbase[i] = lcnt[i] ? atomicAdd(&gcnt[a * NB + i], lcnt[i]) : 0;
        __syncthreads();
        #pragma unroll
        for (int j = 0; j < 16; ++j)
            if (bq[j] >= 0)
                slots[((size_t)a * NB + bq[j]) * SLOTCAP + lbase[bq[j]] + sq[j]] = pq[j];
    }
}

// -------------------- CSR build: scan final counts -> compacted bstart --------------------
__global__ __launch_bounds__(384) void scan_buckets(const int* __restrict__ gcnt,
                                                    int* __restrict__ bstart,
                                                    int* __restrict__ row_start)
{
    const int lane = threadIdx.x & 63, a = threadIdx.x >> 6;
    if (a >= N_ADJS) return;
    int carry = 0;
    #pragma unroll
    for (int c = 0; c < 7; ++c) {
        const int i = c * 64 + lane;
        const int v = (i < NB) ? gcnt[a * NB + i] : 0;
        int xs = v;
        #pragma unroll
        for (int d = 1; d < 64; d <<= 1) { const int t = __shfl_up(xs, d, 64); if (lane >= d) xs += t; }
        const int excl = carry + xs - v;
        if (i < NB) bstart[a * (NB + 1) + i] = excl;
        carry += __shfl(xs, 63, 64);
    }
    if (lane == 0) {
        bstart[a * (NB + 1) + NB] = N_EDGES;
        row_start[(size_t)a * (N_NODES + 1) + N_NODES] = N_EDGES;
    }
}

// -------------------- CSR build, pass B: LDS-staged per-bucket row sort --------------------
// Skips unused adjacencies. Output compressed to 4B/edge: (fp16(val)<<16) | col.
__global__ __launch_bounds__(256) void build_csr(const int2* __restrict__ slots,
                                                 const int* __restrict__ bstart,
                                                 int* __restrict__ row_start,
                                                 unsigned* __restrict__ sorted_cv,
                                                 const int* __restrict__ used)
{
    const int a = blockIdx.y, b = blockIdx.x;
    if (!used[a]) return;
    const int s = bstart[a * (NB + 1) + b];
    const int n = bstart[a * (NB + 1) + b + 1] - s;
    __shared__ int cnt[128], cur[128];
    __shared__ int2 buf[BCAP];       // 22 KB
    __shared__ unsigned buf2[BCAP];  // 11 KB
    if (threadIdx.x < 128) cnt[threadIdx.x] = 0;
    __syncthreads();
    const int2* bk = slots + ((size_t)a * NB + b) * SLOTCAP;
    const bool fits = (n <= BCAP);
    for (int i = threadIdx.x; i < n; i += 256) {
        const int2 p = bk[i];
        if (fits) buf[i] = p;
        atomicAdd(&cnt[(p.x >> 16) & 127], 1);
    }
    __syncthreads();
    const int lane = threadIdx.x & 63, wid = threadIdx.x >> 6;
    if (wid == 0) {
        const int i0 = lane * 2;
        const int c0 = cnt[i0], c1 = cnt[i0 + 1];
        const int sum = c0 + c1;
        int xs = sum;
        #pragma unroll
        for (int d = 1; d < 64; d <<= 1) { const int t = __shfl_up(xs, d, 64); if (lane >= d) xs += t; }
        const int base = xs - sum;        // exclusive, local to bucket
        const int o0 = base, o1 = base + c0;
        cur[i0] = o0; cur[i0 + 1] = o1;
        int* rs = row_start + (size_t)a * (N_NODES + 1);
        const int gr = (b << BSHIFT) + i0;
        if (gr + 0 < N_NODES) rs[gr + 0] = s + o0;
        if (gr + 1 < N_NODES) rs[gr + 1] = s + o1;
    }
    __syncthreads();
    unsigned* sc = sorted_cv + (size_t)a * N_EDGES;
    if (fits) {
        for (int i = threadIdx.x; i < n; i += 256) {
            const int2 p = buf[i];
            const int pos = atomicAdd(&cur[(p.x >> 16) & 127], 1);
            h16cast c16; c16.h = (_Float16)__int_as_float(p.y);
            buf2[pos] = ((unsigned)c16.u << 16) | (unsigned)(p.x & 0xFFFF);
        }
        __syncthreads();
        for (int i = threadIdx.x; i < n; i += 256)
            sc[s + i] = buf2[i];                    // coalesced streaming write
    } else {
        for (int i = threadIdx.x; i < n; i += 256) {
            const int2 p = bk[i];
            const int pos = atomicAdd(&cur[(p.x >> 16) & 127], 1);
            h16cast c16; c16.h = (_Float16)__int_as_float(p.y);
            sc[s + pos] = ((unsigned)c16.u << 16) | (unsigned)(p.x & 0xFFFF);
        }
    }
}

// -------------------- pull-mode SpMM over fp16 states, fp32 accumulate --------------------
static __device__ __forceinline__ void gacc(const _Float16* __restrict__ src,
                                            unsigned cvw, int lane, f32x4& acc)
{
    const int col = (int)(cvw & 0xFFFFu);
    h16cast c16; c16.u = (unsigned short)(cvw >> 16);
    const float v = (float)c16.h;
    const h4 g = *(const h4*)(src + (size_t)col * NHID + lane * 4);
    acc[0] += v * (float)g[0];
    acc[1] += v * (float)g[1];
    acc[2] += v * (float)g[2];
    acc[3] += v * (float)g[3];
}

static __device__ __forceinline__ void pull_part(const int* __restrict__ row_start,
                                                 const unsigned* __restrict__ sorted_cv,
                                                 int a, const _Float16* __restrict__ src,
                                                 int row, int lane, f32x4& acc)
{
    const unsigned* cv = sorted_cv + (size_t)a * N_EDGES;
    const int* rs  = row_start + (size_t)a * (N_NODES + 1);
    const int s = rs[row], epnd = rs[row + 1];
    int e = s;
    for (; e + 3 < epnd; e += 4) {
        const unsigned u0 = cv[e];
        const unsigned u1 = cv[e + 1];
        const unsigned u2 = cv[e + 2];
        const unsigned u3 = cv[e + 3];
        gacc(src, u0, lane, acc);
        gacc(src, u1, lane, acc);
        gacc(src, u2, lane, acc);
        gacc(src, u3, lane, acc);
    }
    for (; e < epnd; ++e) {
        gacc(src, cv[e], lane, acc);
    }
}

template<int PARTS, bool LN>
__global__ __launch_bounds__(256) void pull_spmm(
    const int* __restrict__ row_start, const unsigned* __restrict__ sorted_cv,
    const int* __restrict__ idx_a, int pos_a, const _Float16* __restrict__ src_a,
    const int* __restrict__ idx_b, int pos_b, const _Float16* __restrict__ src_b,
    const int* __restrict__ idx_c, int pos_c, const _Float16* __restrict__ src_c,
    _Float16* __restrict__ outh, float* __restrict__ outf,
    const float* __restrict__ gamma, const float* __restrict__ beta)
{
    const int row  = (blockIdx.x * 256 + threadIdx.x) >> 6;
    const int lane = threadIdx.x & 63;
    if (row >= N_NODES) return;
    f32x4 acc = {0.f, 0.f, 0.f, 0.f};
    pull_part(row_start, sorted_cv, idx_a[pos_a], src_a, row, lane, acc);
    if constexpr (PARTS >= 2) pull_part(row_start, sorted_cv, idx_b[pos_b], src_b, row, lane, acc);
    if constexpr (PARTS >= 3) pull_part(row_start, sorted_cv, idx_c[pos_c], src_c, row, lane, acc);

    if constexpr (LN) {
        float sum = acc[0] + acc[1] + acc[2] + acc[3];
        float sq  = acc[0] * acc[0] + acc[1] * acc[1] + acc[2] * acc[2] + acc[3] * acc[3];
        #pragma unroll
        for (int off = 1; off < 64; off <<= 1) {
            sum += __shfl_xor(sum, off, 64);
            sq  += __shfl_xor(sq,  off, 64);
        }
        const float mu   = sum * (1.f / NHID);
        const float var  = sq * (1.f / NHID) - mu * mu;
        const float rstd = rsqrtf(var + LN_EPS);
        const float4 g4 = *(const float4*)(gamma + lane * 4);
        const float4 b4 = *(const float4*)(beta + lane * 4);
        const float g[4]  = {g4.x, g4.y, g4.z, g4.w};
        const float bb[4] = {b4.x, b4.y, b4.z, b4.w};
        f32x4 o;
        #pragma unroll
        for (int j = 0; j < 4; ++j) {
            const float y = (acc[j] - mu) * rstd * g[j] + bb[j];
            o[j] = 0.5f * y * (1.f + erff(y * 0.70710678118654752f));
        }
        __builtin_nontemporal_store(o, (f32x4*)(outf + (size_t)row * NHID + lane * 4));
    } else {
        h4 o;
        o[0] = (_Float16)acc[0]; o[1] = (_Float16)acc[1];
        o[2] = (_Float16)acc[2]; o[3] = (_Float16)acc[3];
        __builtin_nontemporal_store(o, (h4*)(outh + (size_t)row * NHID + lane * 4));
    }
}

extern "C" void kernel_launch(void* const* d_in, const int* in_sizes, int n_in,
                              void* d_out, int out_size, void* d_ws, size_t ws_size,
                              hipStream_t stream)
{
    (void)in_sizes; (void)n_in; (void)out_size; (void)ws_size;
    const float* x        = (const float*)d_in[0];
    const int* adj_rows   = (const int*)d_in[1];
    const int* adj_cols   = (const int*)d_in[2];
    const float* vals     = (const float*)d_in[3];
    const int* idx_seq    = (const int*)d_in[4];
    const int* idx_res    = (const int*)d_in[5];
    const float* W        = (const float*)d_in[6];
    const float* bias     = (const float*)d_in[7];
    const float* gam      = (const float*)d_in[8];
    const float* bet      = (const float*)d_in[9];

    const size_t S = (size_t)N_NODES * NHID;
    _Float16* s0 = (_Float16*)d_ws;            // 25.6 MB each
    _Float16* s1 = s0 + S;
    _Float16* s2 = s1 + S;
    unsigned* sorted_cv   = (unsigned*)(s2 + S);                              // 19.2 MB
    int*   row_start      = (int*)(sorted_cv + (size_t)N_ADJS * N_EDGES);     // 1.2 MB
    _Float16* Wh          = (_Float16*)(row_start + (size_t)N_ADJS * (N_NODES + 1)); // 128 KB
    int*   gcnt           = (int*)(Wh + NHID * NHID);
    int*   bstart         = gcnt + N_ADJS * NB;
    int*   used           = bstart + N_ADJS * (NB + 1);
    // slots alias s1+s2: 6*391*2560*8 = 48.0 MB <= 51.2 MB; dead before pull1 writes s1.
    int2*  slots          = (int2*)s1;

    convert_w<<<dim3(NHID * NHID / 256), dim3(256), 0, stream>>>(W, Wh, idx_seq, idx_res, used, gcnt);

    // fused: gemm (independent chain) overlaps bucket_scatter (CSR chain)
    gemm_scatter<<<dim3(GB + EB * N_ADJS), dim3(256), 0, stream>>>(
        x, Wh, bias, s0, adj_rows, adj_cols, vals, gcnt, slots, used);

    scan_buckets<<<dim3(1), dim3(384), 0, stream>>>(gcnt, bstart, row_start);
    build_csr<<<dim3(NB, N_ADJS), dim3(256), 0, stream>>>(slots, bstart, row_start, sorted_cv, used);

    const dim3 pgrid(N_NODES * 64 / 256);
    pull_spmm<1, false><<<pgrid, dim3(256), 0, stream>>>(row_start, sorted_cv,
        idx_seq, 0, s0,  nullptr, 0, nullptr,  nullptr, 0, nullptr,
        s1, nullptr, nullptr, nullptr);
    pull_spmm<2, false><<<pgrid, dim3(256), 0, stream>>>(row_start, sorted_cv,
        idx_seq, 1, s1,  idx_res, 0, s0,  nullptr, 0, nullptr,
        s2, nullptr, nullptr, nullptr);
    pull_spmm<3, true><<<pgrid, dim3(256), 0, stream>>>(row_start, sorted_cv,
        idx_seq, 2, s2,  idx_res, 1, s0,  idx_res, 2, s1,
        nullptr, (float*)d_out, gam, bet);
}